// Round 1
// baseline (954.349 us; speedup 1.0000x reference)
//
#include <hip/hip_runtime.h>
#include <hip/hip_bf16.h>
#include <cstdint>
#include <cstddef>

#define SEQ    4096
#define HEADS  32
#define HD     128
#define HIDDEN 2048
#define NINNER 4096
#define BLK    256
#define NB     16

typedef __attribute__((ext_vector_type(8))) __bf16 bf16x8;
typedef __attribute__((ext_vector_type(4))) __bf16 bf16x4;
typedef __attribute__((ext_vector_type(4))) float  f32x4;

#define MFMA16(a,b,c) __builtin_amdgcn_mfma_f32_16x16x32_bf16((a),(b),(c),0,0,0)

typedef __attribute__((address_space(1))) const unsigned int gu32;
typedef __attribute__((address_space(3))) unsigned int lu32;

__device__ __forceinline__ void gld16(void* lds, const void* g){
    __builtin_amdgcn_global_load_lds((gu32*)g, (lu32*)lds, 16, 0, 0);
}

__device__ __forceinline__ float slope_for_head(int h){
    // slopes: 2^(-0.25*(h+1)) * (1 - 0/31 + 1e-5)
    return exp2f(-0.25f*(float)(h+1)) * 1.00001f;
}

// ---------------------------------------------------------------- cast f32->bf16
__global__ __launch_bounds__(256)
void cast_f32_bf16(const float* __restrict__ in, __bf16* __restrict__ out, int n){
    int i = (blockIdx.x*256 + threadIdx.x)*4;
    if (i >= n) return;
    float4 v = *(const float4*)(in + i);
    bf16x4 o;
    o[0] = (__bf16)v.x; o[1] = (__bf16)v.y; o[2] = (__bf16)v.z; o[3] = (__bf16)v.w;
    *(bf16x4*)(out + i) = o;
}

// ---------------------------------------------------------------- W [K][N] f32 -> Wt [N][K] bf16
__global__ __launch_bounds__(256)
void transpose_cast(const float* __restrict__ W, __bf16* __restrict__ Wt, int K, int N){
    __shared__ __align__(16) __bf16 t[64][72];
    const int tid = threadIdx.x;
    const int n0 = blockIdx.x*64, k0 = blockIdx.y*64;
    const int r = tid >> 4, c4 = tid & 15;
    #pragma unroll
    for (int i = 0; i < 4; i++){
        int k = r + i*16;
        float4 v = *(const float4*)(W + (size_t)(k0 + k)*N + n0 + c4*4);
        t[c4*4+0][k] = (__bf16)v.x;
        t[c4*4+1][k] = (__bf16)v.y;
        t[c4*4+2][k] = (__bf16)v.z;
        t[c4*4+3][k] = (__bf16)v.w;
    }
    __syncthreads();
    #pragma unroll
    for (int j = 0; j < 2; j++){
        int idx = tid + j*256;
        int n = idx >> 3, c8 = idx & 7;
        bf16x8 val = *(const bf16x8*)&t[n][c8*8];
        *(bf16x8*)(Wt + (size_t)(n0 + n)*K + k0 + c8*8) = val;
    }
}

// ---------------------------------------------------------------- GEMM C = A @ Bt^T
// A [M][K] bf16 row-major, Bt [N][K] bf16 row-major. 128x128 tile, BK=32.
// EPI 0: silu -> scatter bf16 into qkv[which][h][pos][d]   (N=12288)
// EPI 1: sigmoid -> bf16 [M][N]
// EPI 2: f32 [M][N]
template<int EPI>
__global__ __launch_bounds__(256,2)
void gemm_bt(const __bf16* __restrict__ A, const __bf16* __restrict__ Bt,
             float* __restrict__ Cf, __bf16* __restrict__ Cb,
             int M, int N, int K)
{
    __shared__ __align__(16) __bf16 a_lds[128*32];
    __shared__ __align__(16) __bf16 b_lds[128*32];
    const int tid  = threadIdx.x;
    const int lane = tid & 63;
    const int w    = tid >> 6;
    const int lr   = lane & 15;
    const int quad = lane >> 4;
    const int bn = blockIdx.x, bm = blockIdx.y;
    const int wm = w & 1, wn = w >> 1;

    f32x4 acc[4][4];
    #pragma unroll
    for (int i = 0; i < 4; i++)
        #pragma unroll
        for (int j = 0; j < 4; j++) acc[i][j] = (f32x4){0.f,0.f,0.f,0.f};

    const int srow = lane >> 2;        // 0..15
    const int scol = (lane & 3) * 8;   // 0,8,16,24
    const __bf16* Abase = A  + (size_t)bm*128*K;
    const __bf16* Bbase = Bt + (size_t)bn*128*K;

    for (int kb = 0; kb < K; kb += 32){
        #pragma unroll
        for (int t = 0; t < 2; t++){
            int ch = t*4 + w;   // 0..7, 16 rows each
            gld16(a_lds + ch*512, Abase + (size_t)(ch*16 + srow)*K + kb + scol);
            gld16(b_lds + ch*512, Bbase + (size_t)(ch*16 + srow)*K + kb + scol);
        }
        __syncthreads();
        bf16x8 af[4];
        #pragma unroll
        for (int mt = 0; mt < 4; mt++)
            af[mt] = *(const bf16x8*)&a_lds[(wm*64 + mt*16 + lr)*32 + quad*8];
        #pragma unroll
        for (int nt = 0; nt < 4; nt++){
            bf16x8 bfv = *(const bf16x8*)&b_lds[(wn*64 + nt*16 + lr)*32 + quad*8];
            #pragma unroll
            for (int mt = 0; mt < 4; mt++)
                acc[mt][nt] = MFMA16(af[mt], bfv, acc[mt][nt]);
        }
        __syncthreads();
    }

    if constexpr (EPI == 0){
        const int h = bn / 3, which = bn % 3;
        __bf16* outp = Cb + (size_t)(which*HEADS + h)*SEQ*HD;
        #pragma unroll
        for (int mt = 0; mt < 4; mt++)
        #pragma unroll
        for (int nt = 0; nt < 4; nt++)
        #pragma unroll
        for (int r = 0; r < 4; r++){
            int row = bm*128 + wm*64 + mt*16 + quad*4 + r;  // pos
            int col = wn*64 + nt*16 + lr;                   // d
            float x = acc[mt][nt][r];
            float sv = x / (1.f + __expf(-x));
            outp[(size_t)row*HD + col] = (__bf16)sv;
        }
    } else if constexpr (EPI == 1){
        #pragma unroll
        for (int mt = 0; mt < 4; mt++)
        #pragma unroll
        for (int nt = 0; nt < 4; nt++)
        #pragma unroll
        for (int r = 0; r < 4; r++){
            int row = bm*128 + wm*64 + mt*16 + quad*4 + r;
            int col = bn*128 + wn*64 + nt*16 + lr;
            float x = acc[mt][nt][r];
            Cb[(size_t)row*N + col] = (__bf16)(1.f/(1.f + __expf(-x)));
        }
    } else {
        #pragma unroll
        for (int mt = 0; mt < 4; mt++)
        #pragma unroll
        for (int nt = 0; nt < 4; nt++)
        #pragma unroll
        for (int r = 0; r < 4; r++){
            int row = bm*128 + wm*64 + mt*16 + quad*4 + r;
            int col = bn*128 + wn*64 + nt*16 + lr;
            Cf[(size_t)row*N + col] = acc[mt][nt][r];
        }
    }
}

// ---------------------------------------------------------------- k,v [h][pos][d] -> kT,vT [h][d][pos]
__global__ __launch_bounds__(256)
void prep_T(const __bf16* __restrict__ kbuf, const __bf16* __restrict__ vbuf,
            __bf16* __restrict__ kT, __bf16* __restrict__ vT)
{
    __shared__ __align__(16) __bf16 t[128][136];
    const int tid = threadIdx.x;
    const int pb = blockIdx.x, h = blockIdx.y;
    for (int pass = 0; pass < 2; pass++){
        const __bf16* src = pass ? vbuf : kbuf;
        __bf16* dst = pass ? vT : kT;
        __syncthreads();
        #pragma unroll
        for (int i = 0; i < 8; i++){
            int idx = tid + i*256;
            int row = idx >> 4, c = idx & 15;      // row = pos-local, c*8 = d chunk
            bf16x8 val = *(const bf16x8*)(src + (size_t)(h*SEQ + pb*128 + row)*HD + c*8);
            #pragma unroll
            for (int j = 0; j < 8; j++) t[c*8 + j][row] = val[j];
        }
        __syncthreads();
        #pragma unroll
        for (int i = 0; i < 8; i++){
            int idx = tid + i*256;
            int d = idx >> 4, c = idx & 15;        // c*8 = pos-local chunk
            bf16x8 val = *(const bf16x8*)&t[d][c*8];
            *(bf16x8*)(dst + (size_t)(h*HD + d)*SEQ + pb*128 + c*8) = val;
        }
    }
}

// ---------------------------------------------------------------- pass A: kvbT[h][b][e][d] = sum_i v[i][e]*k[i][d]*kdec(i)
__global__ __launch_bounds__(256,2)
void pass_a(const __bf16* __restrict__ vT, const __bf16* __restrict__ kT,
            float* __restrict__ kvbT)
{
    __shared__ __align__(16) __bf16 a_lds[128*32];
    __shared__ __align__(16) __bf16 b_lds[128*32];
    __shared__ float dec[BLK];
    const int b = blockIdx.x, h = blockIdx.y;
    const float s = slope_for_head(h);
    const int tid = threadIdx.x, lane = tid & 63, w = tid >> 6;
    const int lr = lane & 15, quad = lane >> 4;
    const int wm = w & 1, wn = w >> 1;
    dec[tid] = __expf(-s*(float)(255 - tid));    // k_decay for local pos tid

    f32x4 acc[4][4];
    #pragma unroll
    for (int i = 0; i < 4; i++)
        #pragma unroll
        for (int j = 0; j < 4; j++) acc[i][j] = (f32x4){0.f,0.f,0.f,0.f};

    const int srow = lane >> 2, scol = (lane & 3)*8;
    const __bf16* Abase = vT + (size_t)h*HD*SEQ + (size_t)b*BLK;   // rows e, lda=SEQ
    const __bf16* Bbase = kT + (size_t)h*HD*SEQ + (size_t)b*BLK;   // rows d, ldb=SEQ

    for (int kb = 0; kb < BLK; kb += 32){
        #pragma unroll
        for (int t = 0; t < 2; t++){
            int ch = t*4 + w;
            gld16(a_lds + ch*512, Abase + (size_t)(ch*16 + srow)*SEQ + kb + scol);
            gld16(b_lds + ch*512, Bbase + (size_t)(ch*16 + srow)*SEQ + kb + scol);
        }
        __syncthreads();
        bf16x8 af[4];
        #pragma unroll
        for (int mt = 0; mt < 4; mt++)
            af[mt] = *(const bf16x8*)&a_lds[(wm*64 + mt*16 + lr)*32 + quad*8];
        #pragma unroll
        for (int nt = 0; nt < 4; nt++){
            bf16x8 braw = *(const bf16x8*)&b_lds[(wn*64 + nt*16 + lr)*32 + quad*8];
            #pragma unroll
            for (int j = 0; j < 8; j++){
                float f = (float)braw[j] * dec[kb + quad*8 + j];
                braw[j] = (__bf16)f;
            }
            #pragma unroll
            for (int mt = 0; mt < 4; mt++)
                acc[mt][nt] = MFMA16(af[mt], braw, acc[mt][nt]);
        }
        __syncthreads();
    }
    float* outp = kvbT + (size_t)(h*NB + b)*HD*HD;
    #pragma unroll
    for (int mt = 0; mt < 4; mt++)
    #pragma unroll
    for (int nt = 0; nt < 4; nt++)
    #pragma unroll
    for (int r = 0; r < 4; r++){
        int row = wm*64 + mt*16 + quad*4 + r;   // e
        int col = wn*64 + nt*16 + lr;           // d
        outp[(size_t)row*HD + col] = acc[mt][nt][r];
    }
}

// ---------------------------------------------------------------- pass B: prefix scan of kv states (transposed layout)
__global__ __launch_bounds__(256)
void scan_kv(const float* __restrict__ kvbT, const float* __restrict__ kv0,
             __bf16* __restrict__ kvsT)
{
    const int h = blockIdx.x, t = threadIdx.x;
    const float s = slope_for_head(h);
    const float lam = __expf(-s*(float)BLK);
    float st[64];
    #pragma unroll
    for (int j = 0; j < 64; j++){
        int le = t + 256*j;               // kvT linear index: e*128 + d
        int e = le >> 7, d = le & 127;
        st[j] = kv0[(size_t)h*HD*HD + (size_t)d*HD + e];
    }
    for (int b = 0; b < NB; b++){
        size_t base = (size_t)(h*NB + b)*HD*HD;
        #pragma unroll
        for (int j = 0; j < 64; j++) kvsT[base + t + 256*j] = (__bf16)st[j];
        #pragma unroll
        for (int j = 0; j < 64; j++) st[j] = lam*st[j] + kvbT[base + t + 256*j];
    }
}

// ---------------------------------------------------------------- pass C: out = (q*qdec)@kv + (diag_decay*(q@k^T))@v
__global__ __launch_bounds__(256,2)
void pass_c(const __bf16* __restrict__ qbuf, const __bf16* __restrict__ kbuf,
            const __bf16* __restrict__ vT, const __bf16* __restrict__ kvsT,
            float* __restrict__ attn)
{
    __shared__ __align__(16) __bf16 p_lds[4][64*72];
    const int b = blockIdx.x, h = blockIdx.y;
    const float s = slope_for_head(h);
    const int tid = threadIdx.x, lane = tid & 63, w = tid >> 6;
    const int lr = lane & 15, quad = lane >> 4;

    const __bf16* qh  = qbuf + (size_t)h*SEQ*HD + (size_t)b*BLK*HD;
    const __bf16* kh  = kbuf + (size_t)h*SEQ*HD + (size_t)b*BLK*HD;
    const __bf16* vh  = vT   + (size_t)h*HD*SEQ + (size_t)b*BLK;
    const __bf16* kvh = kvsT + (size_t)(h*NB + b)*HD*HD;

    f32x4 acc[4][8];
    #pragma unroll
    for (int i = 0; i < 4; i++)
        #pragma unroll
        for (int j = 0; j < 8; j++) acc[i][j] = (f32x4){0.f,0.f,0.f,0.f};

    // ---- inter = (q * q_decay) @ kv  (Bt = kvsT[e][d]) ----
    float qdec[4];
    #pragma unroll
    for (int mt = 0; mt < 4; mt++){
        int iloc = w*64 + mt*16 + lr;
        qdec[mt] = __expf(-s*(float)(iloc + 1));
    }
    #pragma unroll
    for (int ks = 0; ks < 4; ks++){
        bf16x8 af[4];
        #pragma unroll
        for (int mt = 0; mt < 4; mt++){
            int iloc = w*64 + mt*16 + lr;
            af[mt] = *(const bf16x8*)(qh + (size_t)iloc*HD + ks*32 + quad*8);
            #pragma unroll
            for (int j = 0; j < 8; j++) af[mt][j] = (__bf16)((float)af[mt][j]*qdec[mt]);
        }
        #pragma unroll
        for (int nt = 0; nt < 8; nt++){
            bf16x8 bv = *(const bf16x8*)(kvh + (size_t)(nt*16 + lr)*HD + ks*32 + quad*8);
            #pragma unroll
            for (int mt = 0; mt < 4; mt++) acc[mt][nt] = MFMA16(af[mt], bv, acc[mt][nt]);
        }
    }

    // ---- intra, in 64-col chunks of the P matrix; wave w owns rows [w*64, w*64+64) ----
    for (int c = 0; c <= w; c++){
        f32x4 qk[4][4];
        #pragma unroll
        for (int i = 0; i < 4; i++)
            #pragma unroll
            for (int j = 0; j < 4; j++) qk[i][j] = (f32x4){0.f,0.f,0.f,0.f};
        #pragma unroll
        for (int ks = 0; ks < 4; ks++){
            bf16x8 af[4];
            #pragma unroll
            for (int mt = 0; mt < 4; mt++)
                af[mt] = *(const bf16x8*)(qh + (size_t)(w*64 + mt*16 + lr)*HD + ks*32 + quad*8);
            #pragma unroll
            for (int nt = 0; nt < 4; nt++){
                bf16x8 kf = *(const bf16x8*)(kh + (size_t)(c*64 + nt*16 + lr)*HD + ks*32 + quad*8);
                #pragma unroll
                for (int mt = 0; mt < 4; mt++) qk[mt][nt] = MFMA16(af[mt], kf, qk[mt][nt]);
            }
        }
        // apply diag decay, P -> per-wave LDS (A-operand layout round-trip)
        #pragma unroll
        for (int mt = 0; mt < 4; mt++)
        #pragma unroll
        for (int nt = 0; nt < 4; nt++)
        #pragma unroll
        for (int r = 0; r < 4; r++){
            int i  = w*64 + mt*16 + quad*4 + r;
            int jj = c*64 + nt*16 + lr;
            int dist = i - jj;
            float dv = (dist >= 0) ? __expf(-s*(float)dist) : 0.f;
            p_lds[w][(mt*16 + quad*4 + r)*72 + nt*16 + lr] = (__bf16)(qk[mt][nt][r]*dv);
        }
        #pragma unroll
        for (int ks2 = 0; ks2 < 2; ks2++){
            bf16x8 pf[4];
            #pragma unroll
            for (int mt = 0; mt < 4; mt++)
                pf[mt] = *(const bf16x8*)&p_lds[w][(mt*16 + lr)*72 + ks2*32 + quad*8];
            #pragma unroll
            for (int nt = 0; nt < 8; nt++){
                bf16x8 vf = *(const bf16x8*)(vh + (size_t)(nt*16 + lr)*SEQ + c*64 + ks2*32 + quad*8);
                #pragma unroll
                for (int mt = 0; mt < 4; mt++) acc[mt][nt] = MFMA16(pf[mt], vf, acc[mt][nt]);
            }
        }
    }

    // ---- epilogue: attn[pos][h*128 + e] (fp32) ----
    #pragma unroll
    for (int mt = 0; mt < 4; mt++)
    #pragma unroll
    for (int nt = 0; nt < 8; nt++)
    #pragma unroll
    for (int r = 0; r < 4; r++){
        int pos = b*BLK + w*64 + mt*16 + quad*4 + r;
        int e = nt*16 + lr;
        attn[(size_t)pos*NINNER + h*HD + e] = acc[mt][nt][r];
    }
}

// ---------------------------------------------------------------- rmsnorm * sigmoid(gate) -> bf16
__global__ __launch_bounds__(256)
void rmsgate(const float* __restrict__ attn, const __bf16* __restrict__ sg,
             const float* __restrict__ nw, __bf16* __restrict__ h2)
{
    const int row = blockIdx.x, tid = threadIdx.x;
    const float* x = attn + (size_t)row*NINNER;
    float4 xs[4];
    float ss = 0.f;
    #pragma unroll
    for (int i = 0; i < 4; i++){
        xs[i] = *(const float4*)(x + (i*256 + tid)*4);
        ss += xs[i].x*xs[i].x + xs[i].y*xs[i].y + xs[i].z*xs[i].z + xs[i].w*xs[i].w;
    }
    #pragma unroll
    for (int o = 32; o > 0; o >>= 1) ss += __shfl_down(ss, o, 64);
    __shared__ float red[4];
    const int lane = tid & 63, w = tid >> 6;
    if (lane == 0) red[w] = ss;
    __syncthreads();
    float tot = red[0] + red[1] + red[2] + red[3];
    float rs = rsqrtf(tot*(1.f/NINNER) + 1e-5f);
    #pragma unroll
    for (int i = 0; i < 4; i++){
        int idx = (i*256 + tid)*4;
        float4 wv = *(const float4*)(nw + idx);
        bf16x4 sv = *(const bf16x4*)(sg + (size_t)row*NINNER + idx);
        bf16x4 o;
        o[0] = (__bf16)((float)sv[0] * xs[i].x*rs*wv.x);
        o[1] = (__bf16)((float)sv[1] * xs[i].y*rs*wv.y);
        o[2] = (__bf16)((float)sv[2] * xs[i].z*rs*wv.z);
        o[3] = (__bf16)((float)sv[3] * xs[i].w*rs*wv.w);
        *(bf16x4*)(h2 + (size_t)row*NINNER + idx) = o;
    }
}

// ================================================================ launch
extern "C" void kernel_launch(void* const* d_in, const int* in_sizes, int n_in,
                              void* d_out, int out_size, void* d_ws, size_t ws_size,
                              hipStream_t stream) {
    (void)in_sizes; (void)n_in; (void)out_size; (void)ws_size;
    const float* hs    = (const float*)d_in[0];
    const float* kv0   = (const float*)d_in[2];
    const float* Wqkv  = (const float*)d_in[3];
    const float* Wgate = (const float*)d_in[4];
    const float* Wout  = (const float*)d_in[5];
    const float* nw    = (const float*)d_in[6];
    float* out = (float*)d_out;

    char* ws = (char*)d_ws;
    // region0: WqkvT(50.3MB)+WgateT(16.8MB), later aliased by attn fp32 (67.1MB exact)
    __bf16* WqkvT  = (__bf16*)(ws);
    __bf16* WgateT = (__bf16*)(ws + 50331648);
    float*  attn   = (float*)(ws);
    __bf16* WoutT  = (__bf16*)(ws + 67108864);
    __bf16* hsb    = (__bf16*)(ws + 83886080);
    __bf16* qkvb   = (__bf16*)(ws + 100663296);           // [which][h][pos][d], 100.7MB
    __bf16* qbuf   = qkvb;
    __bf16* kbuf   = qkvb + (size_t)HEADS*SEQ*HD;
    __bf16* vbuf   = qkvb + (size_t)2*HEADS*SEQ*HD;
    __bf16* h2     = qkvb;                                // alias q after pass_c
    __bf16* kT     = (__bf16*)(ws + 201326592);
    __bf16* vT     = (__bf16*)(ws + 234881024);
    float*  kvbT   = (float*) (ws + 268435456);
    __bf16* kvsT   = (__bf16*)(ws + 301989888);
    __bf16* sgate  = (__bf16*)(ws + 318767104);
    // total: 352321536 bytes

    cast_f32_bf16<<<8192, 256, 0, stream>>>(hs, hsb, SEQ*HIDDEN);
    transpose_cast<<<dim3(192, 32), 256, 0, stream>>>(Wqkv,  WqkvT,  2048, 12288);
    transpose_cast<<<dim3( 64, 32), 256, 0, stream>>>(Wgate, WgateT, 2048,  4096);
    transpose_cast<<<dim3( 32, 64), 256, 0, stream>>>(Wout,  WoutT,  4096,  2048);

    gemm_bt<0><<<dim3(96, 32), 256, 0, stream>>>(hsb, WqkvT, nullptr, qkvb, 4096, 12288, 2048);
    gemm_bt<1><<<dim3(32, 32), 256, 0, stream>>>(hsb, WgateT, nullptr, sgate, 4096, 4096, 2048);

    prep_T<<<dim3(32, 32), 256, 0, stream>>>(kbuf, vbuf, kT, vT);
    pass_a<<<dim3(16, 32), 256, 0, stream>>>(vT, kT, kvbT);
    scan_kv<<<32, 256, 0, stream>>>(kvbT, kv0, kvsT);
    pass_c<<<dim3(16, 32), 256, 0, stream>>>(qbuf, kbuf, vT, kvsT, attn);

    rmsgate<<<4096, 256, 0, stream>>>(attn, sgate, nw, h2);
    gemm_bt<2><<<dim3(16, 32), 256, 0, stream>>>(h2, WoutT, out, nullptr, 4096, 2048, 4096);
}

// Round 2
// 776.037 us; speedup vs baseline: 1.2298x; 1.2298x over previous
//
#include <hip/hip_runtime.h>
#include <hip/hip_bf16.h>
#include <cstdint>
#include <cstddef>

#define SEQ    4096
#define HEADS  32
#define HD     128
#define HIDDEN 2048
#define NINNER 4096
#define BLK    256
#define NB     16

typedef __attribute__((ext_vector_type(8))) __bf16 bf16x8;
typedef __attribute__((ext_vector_type(4))) __bf16 bf16x4;
typedef __attribute__((ext_vector_type(4))) float  f32x4;

#define MFMA16(a,b,c) __builtin_amdgcn_mfma_f32_16x16x32_bf16((a),(b),(c),0,0,0)

typedef __attribute__((address_space(1))) const unsigned int gu32;
typedef __attribute__((address_space(3))) unsigned int lu32;

__device__ __forceinline__ void gld16(void* lds, const void* g){
    __builtin_amdgcn_global_load_lds((gu32*)g, (lu32*)lds, 16, 0, 0);
}

__device__ __forceinline__ float slope_for_head(int h){
    return exp2f(-0.25f*(float)(h+1)) * 1.00001f;
}

// ---------------------------------------------------------------- cast f32->bf16
__global__ __launch_bounds__(256)
void cast_f32_bf16(const float* __restrict__ in, __bf16* __restrict__ out, int n){
    int i = (blockIdx.x*256 + threadIdx.x)*4;
    if (i >= n) return;
    float4 v = *(const float4*)(in + i);
    bf16x4 o;
    o[0] = (__bf16)v.x; o[1] = (__bf16)v.y; o[2] = (__bf16)v.z; o[3] = (__bf16)v.w;
    *(bf16x4*)(out + i) = o;
}

// ---------------------------------------------------------------- W [K][N] f32 -> Wt [N][K] bf16
__global__ __launch_bounds__(256)
void transpose_cast(const float* __restrict__ W, __bf16* __restrict__ Wt, int K, int N){
    __shared__ __align__(16) __bf16 t[64][72];
    const int tid = threadIdx.x;
    const int n0 = blockIdx.x*64, k0 = blockIdx.y*64;
    const int r = tid >> 4, c4 = tid & 15;
    #pragma unroll
    for (int i = 0; i < 4; i++){
        int k = r + i*16;
        float4 v = *(const float4*)(W + (size_t)(k0 + k)*N + n0 + c4*4);
        t[c4*4+0][k] = (__bf16)v.x;
        t[c4*4+1][k] = (__bf16)v.y;
        t[c4*4+2][k] = (__bf16)v.z;
        t[c4*4+3][k] = (__bf16)v.w;
    }
    __syncthreads();
    #pragma unroll
    for (int j = 0; j < 2; j++){
        int idx = tid + j*256;
        int n = idx >> 3, c8 = idx & 7;
        bf16x8 val = *(const bf16x8*)&t[n][c8*8];
        *(bf16x8*)(Wt + (size_t)(n0 + n)*K + k0 + c8*8) = val;
    }
}

// ---------------------------------------------------------------- GEMM C = A @ Bt^T
// A [M][K] bf16, Bt [N][K] bf16. 128x128 tile, BK=64, XOR-swizzled LDS.
// EPI 0: fused qkv+gate. bn<96: silu -> qkv scatter; bn>=96: sigmoid -> sgate.
// EPI 2: f32 [M][N].
template<int EPI>
__global__ __launch_bounds__(256,2)
void gemm_bt(const __bf16* __restrict__ A, const __bf16* __restrict__ Bt,
             float* __restrict__ Cf, __bf16* __restrict__ Cb, __bf16* __restrict__ Cb2,
             int M, int N, int K)
{
    __shared__ __align__(16) __bf16 a_lds[128*64];
    __shared__ __align__(16) __bf16 b_lds[128*64];
    const int tid  = threadIdx.x;
    const int lane = tid & 63;
    const int w    = tid >> 6;
    const int lr   = lane & 15;
    const int quad = lane >> 4;
    const int bn = blockIdx.x, bm = blockIdx.y;
    const int wm = w & 1, wn = w >> 1;

    f32x4 acc[4][4];
    #pragma unroll
    for (int i = 0; i < 4; i++)
        #pragma unroll
        for (int j = 0; j < 4; j++) acc[i][j] = (f32x4){0.f,0.f,0.f,0.f};

    // staging: chunk = 8 rows x 8 granules(16B). lane -> row r8, swizzled granule qs.
    const int r8 = lane >> 3;            // 0..7
    const int qs = (lane & 7) ^ r8;      // XOR swizzle
    const __bf16* Abase = A  + (size_t)bm*128*K;
    const __bf16* Bbase = Bt + (size_t)bn*128*K;

    // fragment read offsets (element): row*64 + ((Q ^ (row&7))*8)
    const int sw = lr & 7;

    for (int kb = 0; kb < K; kb += 64){
        #pragma unroll
        for (int t = 0; t < 4; t++){
            int ch = t*4 + w;   // 0..15, 8 rows each
            gld16(a_lds + ch*512, Abase + (size_t)(ch*8 + r8)*K + kb + qs*8);
            gld16(b_lds + ch*512, Bbase + (size_t)(ch*8 + r8)*K + kb + qs*8);
        }
        __syncthreads();
        #pragma unroll
        for (int kk = 0; kk < 2; kk++){
            bf16x8 af[4];
            #pragma unroll
            for (int mt = 0; mt < 4; mt++)
                af[mt] = *(const bf16x8*)&a_lds[(wm*64 + mt*16 + lr)*64 + (((kk*4+quad) ^ sw)*8)];
            #pragma unroll
            for (int nt = 0; nt < 4; nt++){
                bf16x8 bfv = *(const bf16x8*)&b_lds[(wn*64 + nt*16 + lr)*64 + (((kk*4+quad) ^ sw)*8)];
                #pragma unroll
                for (int mt = 0; mt < 4; mt++)
                    acc[mt][nt] = MFMA16(af[mt], bfv, acc[mt][nt]);
            }
        }
        __syncthreads();
    }

    if constexpr (EPI == 0){
        if (bn < 96){
            const int h = bn / 3, which = bn % 3;
            __bf16* outp = Cb + (size_t)(which*HEADS + h)*SEQ*HD;
            #pragma unroll
            for (int mt = 0; mt < 4; mt++)
            #pragma unroll
            for (int nt = 0; nt < 4; nt++)
            #pragma unroll
            for (int r = 0; r < 4; r++){
                int row = bm*128 + wm*64 + mt*16 + quad*4 + r;  // pos
                int col = wn*64 + nt*16 + lr;                   // d
                float x = acc[mt][nt][r];
                float sv = x / (1.f + __expf(-x));
                outp[(size_t)row*HD + col] = (__bf16)sv;
            }
        } else {
            const int col0 = (bn - 96)*128;
            #pragma unroll
            for (int mt = 0; mt < 4; mt++)
            #pragma unroll
            for (int nt = 0; nt < 4; nt++)
            #pragma unroll
            for (int r = 0; r < 4; r++){
                int row = bm*128 + wm*64 + mt*16 + quad*4 + r;
                int col = col0 + wn*64 + nt*16 + lr;
                float x = acc[mt][nt][r];
                Cb2[(size_t)row*NINNER + col] = (__bf16)(1.f/(1.f + __expf(-x)));
            }
        }
    } else {
        #pragma unroll
        for (int mt = 0; mt < 4; mt++)
        #pragma unroll
        for (int nt = 0; nt < 4; nt++)
        #pragma unroll
        for (int r = 0; r < 4; r++){
            int row = bm*128 + wm*64 + mt*16 + quad*4 + r;
            int col = bn*128 + wn*64 + nt*16 + lr;
            Cf[(size_t)row*N + col] = acc[mt][nt][r];
        }
    }
}

// ---------------------------------------------------------------- k,v [h][pos][d] -> kT,vT [h][d][pos]
// k additionally scaled by k_decay(pos%256) so pass_a is a pure GEMM.
__global__ __launch_bounds__(256)
void prep_T(const __bf16* __restrict__ kbuf, const __bf16* __restrict__ vbuf,
            __bf16* __restrict__ kT, __bf16* __restrict__ vT)
{
    __shared__ __align__(16) __bf16 t[128][136];
    const int tid = threadIdx.x;
    const int pb = blockIdx.x, h = blockIdx.y;
    const float s = slope_for_head(h);
    const int locbase = (pb & 1)*128;     // local pos within 256-block
    for (int pass = 0; pass < 2; pass++){
        const __bf16* src = pass ? vbuf : kbuf;
        __bf16* dst = pass ? vT : kT;
        __syncthreads();
        #pragma unroll
        for (int i = 0; i < 8; i++){
            int idx = tid + i*256;
            int row = idx >> 4, c = idx & 15;
            bf16x8 val = *(const bf16x8*)(src + (size_t)(h*SEQ + pb*128 + row)*HD + c*8);
            if (pass == 0){
                float dec = __expf(-s*(float)(255 - (locbase + row)));
                #pragma unroll
                for (int j = 0; j < 8; j++) val[j] = (__bf16)((float)val[j]*dec);
            }
            #pragma unroll
            for (int j = 0; j < 8; j++) t[c*8 + j][row] = val[j];
        }
        __syncthreads();
        #pragma unroll
        for (int i = 0; i < 8; i++){
            int idx = tid + i*256;
            int d = idx >> 4, c = idx & 15;
            bf16x8 val = *(const bf16x8*)&t[d][c*8];
            *(bf16x8*)(dst + (size_t)(h*HD + d)*SEQ + pb*128 + c*8) = val;
        }
    }
}

// ---------------------------------------------------------------- pass A: kvbT[h][b][e][d] = sum_i v[i][e]*kdec[i][d]
// pure GEMM: A = vT rows (e, lda=SEQ), B = kT rows (d, ldb=SEQ), K = 256 local positions.
__global__ __launch_bounds__(256,2)
void pass_a(const __bf16* __restrict__ vT, const __bf16* __restrict__ kT,
            float* __restrict__ kvbT)
{
    __shared__ __align__(16) __bf16 a_lds[128*64];
    __shared__ __align__(16) __bf16 b_lds[128*64];
    const int b = blockIdx.x, h = blockIdx.y;
    const int tid = threadIdx.x, lane = tid & 63, w = tid >> 6;
    const int lr = lane & 15, quad = lane >> 4;
    const int wm = w & 1, wn = w >> 1;

    f32x4 acc[4][4];
    #pragma unroll
    for (int i = 0; i < 4; i++)
        #pragma unroll
        for (int j = 0; j < 4; j++) acc[i][j] = (f32x4){0.f,0.f,0.f,0.f};

    const int r8 = lane >> 3;
    const int qs = (lane & 7) ^ r8;
    const int sw = lr & 7;
    const __bf16* Abase = vT + (size_t)h*HD*SEQ + (size_t)b*BLK;
    const __bf16* Bbase = kT + (size_t)h*HD*SEQ + (size_t)b*BLK;

    for (int kb = 0; kb < BLK; kb += 64){
        #pragma unroll
        for (int t = 0; t < 4; t++){
            int ch = t*4 + w;
            gld16(a_lds + ch*512, Abase + (size_t)(ch*8 + r8)*SEQ + kb + qs*8);
            gld16(b_lds + ch*512, Bbase + (size_t)(ch*8 + r8)*SEQ + kb + qs*8);
        }
        __syncthreads();
        #pragma unroll
        for (int kk = 0; kk < 2; kk++){
            bf16x8 af[4];
            #pragma unroll
            for (int mt = 0; mt < 4; mt++)
                af[mt] = *(const bf16x8*)&a_lds[(wm*64 + mt*16 + lr)*64 + (((kk*4+quad) ^ sw)*8)];
            #pragma unroll
            for (int nt = 0; nt < 4; nt++){
                bf16x8 bfv = *(const bf16x8*)&b_lds[(wn*64 + nt*16 + lr)*64 + (((kk*4+quad) ^ sw)*8)];
                #pragma unroll
                for (int mt = 0; mt < 4; mt++)
                    acc[mt][nt] = MFMA16(af[mt], bfv, acc[mt][nt]);
            }
        }
        __syncthreads();
    }
    float* outp = kvbT + (size_t)(h*NB + b)*HD*HD;
    #pragma unroll
    for (int mt = 0; mt < 4; mt++)
    #pragma unroll
    for (int nt = 0; nt < 4; nt++)
    #pragma unroll
    for (int r = 0; r < 4; r++){
        int row = wm*64 + mt*16 + quad*4 + r;   // e
        int col = wn*64 + nt*16 + lr;           // d
        outp[(size_t)row*HD + col] = acc[mt][nt][r];
    }
}

// ---------------------------------------------------------------- pass B: prefix scan, e-dim split for parallelism
__global__ __launch_bounds__(256)
void scan_kv(const float* __restrict__ kvbT, const float* __restrict__ kv0,
             __bf16* __restrict__ kvsT)
{
    const int chunk = blockIdx.x;   // 0..7
    const int h = blockIdx.y;
    const int t = threadIdx.x;
    const float s = slope_for_head(h);
    const float lam = __expf(-s*(float)BLK);
    const int le0 = chunk*2048;
    float st[8];
    #pragma unroll
    for (int j = 0; j < 8; j++){
        int le = le0 + t + 256*j;         // index into [e][d] layout
        int e = le >> 7, d = le & 127;
        st[j] = kv0[(size_t)h*HD*HD + (size_t)d*HD + e];
    }
    for (int b = 0; b < NB; b++){
        size_t base = (size_t)(h*NB + b)*HD*HD + le0;
        #pragma unroll
        for (int j = 0; j < 8; j++) kvsT[base + t + 256*j] = (__bf16)st[j];
        #pragma unroll
        for (int j = 0; j < 8; j++) st[j] = lam*st[j] + kvbT[base + t + 256*j];
    }
}

// ---------------------------------------------------------------- pass C: out = (q*qdec)@kv + (diag_decay*(q@k^T))@v
// grid (NB*2, HEADS): block handles 128 rows; wave w owns 32 rows.
__global__ __launch_bounds__(256,2)
void pass_c(const __bf16* __restrict__ qbuf, const __bf16* __restrict__ kbuf,
            const __bf16* __restrict__ vT, const __bf16* __restrict__ kvsT,
            float* __restrict__ attn)
{
    __shared__ __align__(16) __bf16 p_lds[4][32*72];
    const int rb = blockIdx.x & 1, b = blockIdx.x >> 1, h = blockIdx.y;
    const float s = slope_for_head(h);
    const int tid = threadIdx.x, lane = tid & 63, w = tid >> 6;
    const int lr = lane & 15, quad = lane >> 4;
    const int R0 = rb*128 + w*32;          // local row base for this wave

    const __bf16* qh  = qbuf + (size_t)h*SEQ*HD + (size_t)b*BLK*HD;
    const __bf16* kh  = kbuf + (size_t)h*SEQ*HD + (size_t)b*BLK*HD;
    const __bf16* vh  = vT   + (size_t)h*HD*SEQ + (size_t)b*BLK;
    const __bf16* kvh = kvsT + (size_t)(h*NB + b)*HD*HD;

    f32x4 acc[2][8];
    #pragma unroll
    for (int i = 0; i < 2; i++)
        #pragma unroll
        for (int j = 0; j < 8; j++) acc[i][j] = (f32x4){0.f,0.f,0.f,0.f};

    // hoisted q fragments (A-layout rows R0+mt*16+lr)
    bf16x8 qf[4][2];
    #pragma unroll
    for (int ks = 0; ks < 4; ks++)
        #pragma unroll
        for (int mt = 0; mt < 2; mt++)
            qf[ks][mt] = *(const bf16x8*)(qh + (size_t)(R0 + mt*16 + lr)*HD + ks*32 + quad*8);

    // ---- inter = (q * q_decay) @ kvsT ----
    float qdec[2];
    #pragma unroll
    for (int mt = 0; mt < 2; mt++)
        qdec[mt] = __expf(-s*(float)(R0 + mt*16 + lr + 1));
    #pragma unroll
    for (int ks = 0; ks < 4; ks++){
        bf16x8 saf[2];
        #pragma unroll
        for (int mt = 0; mt < 2; mt++)
            #pragma unroll
            for (int j = 0; j < 8; j++) saf[mt][j] = (__bf16)((float)qf[ks][mt][j]*qdec[mt]);
        #pragma unroll
        for (int nt = 0; nt < 8; nt++){
            bf16x8 bv = *(const bf16x8*)(kvh + (size_t)(nt*16 + lr)*HD + ks*32 + quad*8);
            #pragma unroll
            for (int mt = 0; mt < 2; mt++) acc[mt][nt] = MFMA16(saf[mt], bv, acc[mt][nt]);
        }
    }

    // ---- intra: 64-col chunks c = 0..cmax ----
    float colf[4];
    #pragma unroll
    for (int nt = 0; nt < 4; nt++)
        colf[nt] = __expf(-s*(float)(63 - nt*16 - lr));   // exp(s*(jloc-63)) <= 1
    const int cmax = (R0 + 31) >> 6;
    for (int c = 0; c <= cmax; c++){
        f32x4 qk[2][4];
        #pragma unroll
        for (int i = 0; i < 2; i++)
            #pragma unroll
            for (int j = 0; j < 4; j++) qk[i][j] = (f32x4){0.f,0.f,0.f,0.f};
        #pragma unroll
        for (int ks = 0; ks < 4; ks++){
            #pragma unroll
            for (int nt = 0; nt < 4; nt++){
                bf16x8 kf = *(const bf16x8*)(kh + (size_t)(c*64 + nt*16 + lr)*HD + ks*32 + quad*8);
                #pragma unroll
                for (int mt = 0; mt < 2; mt++) qk[mt][nt] = MFMA16(qf[ks][mt], kf, qk[mt][nt]);
            }
        }
        // decay: dv = exp(-s*(i - c*64 - 63)) * exp(-s*(63 - jloc)), masked for dist<0
        float rowf[2][4];
        #pragma unroll
        for (int mt = 0; mt < 2; mt++)
            #pragma unroll
            for (int r = 0; r < 4; r++)
                rowf[mt][r] = __expf(-s*(float)(R0 + mt*16 + quad*4 + r - c*64 - 63));
        #pragma unroll
        for (int mt = 0; mt < 2; mt++)
        #pragma unroll
        for (int nt = 0; nt < 4; nt++)
        #pragma unroll
        for (int r = 0; r < 4; r++){
            int i  = R0 + mt*16 + quad*4 + r;
            int jj = c*64 + nt*16 + lr;
            float dv = (i >= jj) ? rowf[mt][r]*colf[nt] : 0.f;
            p_lds[w][(mt*16 + quad*4 + r)*72 + nt*16 + lr] = (__bf16)(qk[mt][nt][r]*dv);
        }
        #pragma unroll
        for (int ks2 = 0; ks2 < 2; ks2++){
            bf16x8 pf[2];
            #pragma unroll
            for (int mt = 0; mt < 2; mt++)
                pf[mt] = *(const bf16x8*)&p_lds[w][(mt*16 + lr)*72 + ks2*32 + quad*8];
            #pragma unroll
            for (int nt = 0; nt < 8; nt++){
                bf16x8 vf = *(const bf16x8*)(vh + (size_t)(nt*16 + lr)*SEQ + c*64 + ks2*32 + quad*8);
                #pragma unroll
                for (int mt = 0; mt < 2; mt++) acc[mt][nt] = MFMA16(pf[mt], vf, acc[mt][nt]);
            }
        }
    }

    // ---- epilogue: attn[pos][h*128 + e] (fp32) ----
    #pragma unroll
    for (int mt = 0; mt < 2; mt++)
    #pragma unroll
    for (int nt = 0; nt < 8; nt++)
    #pragma unroll
    for (int r = 0; r < 4; r++){
        int pos = b*BLK + R0 + mt*16 + quad*4 + r;
        int e = nt*16 + lr;
        attn[(size_t)pos*NINNER + h*HD + e] = acc[mt][nt][r];
    }
}

// ---------------------------------------------------------------- rmsnorm * sigmoid(gate) -> bf16
__global__ __launch_bounds__(256)
void rmsgate(const float* __restrict__ attn, const __bf16* __restrict__ sg,
             const float* __restrict__ nw, __bf16* __restrict__ h2)
{
    const int row = blockIdx.x, tid = threadIdx.x;
    const float* x = attn + (size_t)row*NINNER;
    float4 xs[4];
    float ss = 0.f;
    #pragma unroll
    for (int i = 0; i < 4; i++){
        xs[i] = *(const float4*)(x + (i*256 + tid)*4);
        ss += xs[i].x*xs[i].x + xs[i].y*xs[i].y + xs[i].z*xs[i].z + xs[i].w*xs[i].w;
    }
    #pragma unroll
    for (int o = 32; o > 0; o >>= 1) ss += __shfl_down(ss, o, 64);
    __shared__ float red[4];
    const int lane = tid & 63, w = tid >> 6;
    if (lane == 0) red[w] = ss;
    __syncthreads();
    float tot = red[0] + red[1] + red[2] + red[3];
    float rs = rsqrtf(tot*(1.f/NINNER) + 1e-5f);
    #pragma unroll
    for (int i = 0; i < 4; i++){
        int idx = (i*256 + tid)*4;
        float4 wv = *(const float4*)(nw + idx);
        bf16x4 sv = *(const bf16x4*)(sg + (size_t)row*NINNER + idx);
        bf16x4 o;
        o[0] = (__bf16)((float)sv[0] * xs[i].x*rs*wv.x);
        o[1] = (__bf16)((float)sv[1] * xs[i].y*rs*wv.y);
        o[2] = (__bf16)((float)sv[2] * xs[i].z*rs*wv.z);
        o[3] = (__bf16)((float)sv[3] * xs[i].w*rs*wv.w);
        *(bf16x4*)(h2 + (size_t)row*NINNER + idx) = o;
    }
}

// ================================================================ launch
extern "C" void kernel_launch(void* const* d_in, const int* in_sizes, int n_in,
                              void* d_out, int out_size, void* d_ws, size_t ws_size,
                              hipStream_t stream) {
    (void)in_sizes; (void)n_in; (void)out_size; (void)ws_size;
    const float* hs    = (const float*)d_in[0];
    const float* kv0   = (const float*)d_in[2];
    const float* Wqkv  = (const float*)d_in[3];
    const float* Wgate = (const float*)d_in[4];
    const float* Wout  = (const float*)d_in[5];
    const float* nw    = (const float*)d_in[6];
    float* out = (float*)d_out;

    char* ws = (char*)d_ws;
    // region0: WqkvT(50.3MB)+WgateT(16.8MB) contiguous (fused GEMM weight), later aliased by attn fp32
    __bf16* WqkvT  = (__bf16*)(ws);
    __bf16* WgateT = (__bf16*)(ws + 50331648);
    float*  attn   = (float*)(ws);
    __bf16* WoutT  = (__bf16*)(ws + 67108864);
    __bf16* hsb    = (__bf16*)(ws + 83886080);
    __bf16* qkvb   = (__bf16*)(ws + 100663296);           // [which][h][pos][d]
    __bf16* qbuf   = qkvb;
    __bf16* kbuf   = qkvb + (size_t)HEADS*SEQ*HD;
    __bf16* vbuf   = qkvb + (size_t)2*HEADS*SEQ*HD;
    __bf16* h2     = qkvb;                                // alias q after pass_c
    __bf16* kT     = (__bf16*)(ws + 201326592);
    __bf16* vT     = (__bf16*)(ws + 234881024);
    float*  kvbT   = (float*) (ws + 268435456);
    __bf16* kvsT   = (__bf16*)(ws + 301989888);
    __bf16* sgate  = (__bf16*)(ws + 318767104);

    cast_f32_bf16<<<8192, 256, 0, stream>>>(hs, hsb, SEQ*HIDDEN);
    transpose_cast<<<dim3(192, 32), 256, 0, stream>>>(Wqkv,  WqkvT,  2048, 12288);
    transpose_cast<<<dim3( 64, 32), 256, 0, stream>>>(Wgate, WgateT, 2048,  4096);
    transpose_cast<<<dim3( 32, 64), 256, 0, stream>>>(Wout,  WoutT,  4096,  2048);

    // fused qkv+gate: N = 12288 + 4096 = 16384 (weights contiguous in ws)
    gemm_bt<0><<<dim3(128, 32), 256, 0, stream>>>(hsb, WqkvT, nullptr, qkvb, sgate, 4096, 16384, 2048);

    prep_T<<<dim3(32, 32), 256, 0, stream>>>(kbuf, vbuf, kT, vT);
    pass_a<<<dim3(16, 32), 256, 0, stream>>>(vT, kT, kvbT);
    scan_kv<<<dim3(8, 32), 256, 0, stream>>>(kvbT, kv0, kvsT);
    pass_c<<<dim3(NB*2, 32), 256, 0, stream>>>(qbuf, kbuf, vT, kvsT, attn);

    rmsgate<<<4096, 256, 0, stream>>>(attn, sgate, nw, h2);
    gemm_bt<2><<<dim3(16, 32), 256, 0, stream>>>(h2, WoutT, out, nullptr, nullptr, 4096, 2048, 4096);
}